// Round 15
// baseline (178.831 us; speedup 1.0000x reference)
//
#include <hip/hip_runtime.h>

typedef _Float16 half_t;
typedef __attribute__((ext_vector_type(8))) _Float16 half8;
typedef __attribute__((ext_vector_type(4))) _Float16 half4;
typedef __attribute__((ext_vector_type(4))) float f32x4;
typedef __attribute__((ext_vector_type(16))) float f32x16;

#define TSEQ   2048
#define DMODEL 1024
#define K2LOG  0.18033688011116016f   /* 0.125 * log2(e) */

#if __has_builtin(__builtin_amdgcn_exp2f)
#define EXP2F(x) __builtin_amdgcn_exp2f(x)
#else
#define EXP2F(x) __expf(0.6931471805599453f * (x))
#endif

__device__ inline unsigned pk2(float a, float b) {
  auto h = __builtin_amdgcn_cvt_pkrtz(a, b);   // __fp16 ext_vector(2)
  return __builtin_bit_cast(unsigned, h);
}
__device__ inline half8 frag_from(unsigned a, unsigned b, unsigned c, unsigned d) {
  int4 t; t.x = (int)a; t.y = (int)b; t.z = (int)c; t.w = (int)d;
  return __builtin_bit_cast(half8, t);
}

#if __has_builtin(__builtin_amdgcn_permlane32_swap)
__device__ inline void pl32(unsigned &a, unsigned &b) {
  auto r = __builtin_amdgcn_permlane32_swap(a, b, false, false);
  a = (unsigned)r[0]; b = (unsigned)r[1];
}
#else
__device__ inline void pl32(unsigned &a, unsigned &b) {
  const int hi = (threadIdx.x & 63) >> 5;
  unsigned sa = __shfl_xor(a, 32), sb = __shfl_xor(b, 32);
  unsigned na = hi ? sb : a;
  unsigned nb = hi ? b : sa;
  a = na; b = nb;
}
#endif
__device__ inline float partner32(float v, int hi) {
  unsigned a = __builtin_bit_cast(unsigned, v), b = a;
  pl32(a, b);
  return __builtin_bit_cast(float, hi ? a : b);
}

// ================== async global->LDS staging ==================
#define GLD_LDS(g, l) \
  __builtin_amdgcn_global_load_lds((const __attribute__((address_space(1))) void*)(g), \
                                   (__attribute__((address_space(3))) void*)(l), 16, 0, 0)

// ---------- fused prep: LN (blocks 0..4095) + W transposes (blocks 4096..8191) ----------
__global__ void k_prep(const float* __restrict__ x, const float* __restrict__ gamma,
                       const float* __restrict__ beta, half_t* __restrict__ xn,
                       const float* __restrict__ wqkv, half_t* __restrict__ wqt,
                       const float* __restrict__ wproj, half_t* __restrict__ wpt) {
  __shared__ float sm[32 * 33];
  const int blk = blockIdx.x;
  if (blk < 4096) {
    int row = blk, t = threadIdx.x;
    const float4 v = *(const float4*)(x + (size_t)row * DMODEL + t * 4);
    float s  = v.x + v.y + v.z + v.w;
    float ss = v.x * v.x + v.y * v.y + v.z * v.z + v.w * v.w;
#pragma unroll
    for (int off = 32; off >= 1; off >>= 1) {
      s  += __shfl_down(s, off);
      ss += __shfl_down(ss, off);
    }
    int wid = t >> 6;
    if ((t & 63) == 0) { sm[wid] = s; sm[4 + wid] = ss; }
    __syncthreads();
    s  = sm[0] + sm[1] + sm[2] + sm[3];
    ss = sm[4] + sm[5] + sm[6] + sm[7];
    float mu   = s * (1.f / DMODEL);
    float var  = ss * (1.f / DMODEL) - mu * mu;
    float rstd = rsqrtf(var + 1e-5f);
    float4 g = *(const float4*)(gamma + t * 4);
    float4 b = *(const float4*)(beta  + t * 4);
    half4 o;
    o.x = (half_t)((v.x - mu) * rstd * g.x + b.x);
    o.y = (half_t)((v.y - mu) * rstd * g.y + b.y);
    o.z = (half_t)((v.z - mu) * rstd * g.z + b.z);
    o.w = (half_t)((v.w - mu) * rstd * g.w + b.w);
    *(half4*)(xn + (size_t)row * DMODEL + t * 4) = o;
  } else {
    const int bx2 = blk - 4096;
    const int bx = bx2 & 127, by = bx2 >> 7;
    const float* in;
    half_t* out;
    int n0, N;
    if (bx < 96) { in = wqkv; out = wqt; n0 = bx * 32; N = 3072; }
    else         { in = wproj; out = wpt; n0 = (bx - 96) * 32; N = 1024; }
    int k0 = by * 32;
    int tx = threadIdx.x & 31, ty = threadIdx.x >> 5;
#pragma unroll
    for (int i = 0; i < 32; i += 8)
      sm[(ty + i) * 33 + tx] = in[(size_t)(k0 + ty + i) * N + n0 + tx];
    __syncthreads();
#pragma unroll
    for (int i = 0; i < 32; i += 8)
      out[(size_t)(n0 + ty + i) * 1024 + k0 + tx] = (half_t)sm[tx * 33 + ty + i];
  }
}

// ---------- QKV GEMM: 256x256 tile, 8-phase interleave, counted vmcnt (T3+T4) ----------
__global__ __launch_bounds__(512, 2) void k_gemm_qkv(
    const half_t* __restrict__ A,   // xn [4096][1024]
    const half_t* __restrict__ Bt,  // Wqkv^T [3072][1024]
    const float* __restrict__ bias, // [3072]
    half_t* __restrict__ qh, half_t* __restrict__ kh, half_t* __restrict__ vt) {
  extern __shared__ __align__(16) char smem[];   // 128 KB
  char* smA = smem;
  char* smB = smem + 65536;

  const int p = blockIdx.x;
  const int lb = (p & 7) * 24 + (p >> 3);
  const int mt = lb & 15, nt = lb >> 4;      // mt 0..15, nt 0..11

  const int tid = threadIdx.x, lane = tid & 63, wid = tid >> 6;
  const int wr = wid >> 2, wc = wid & 3;
  const int col = lane & 15, kg = lane >> 4;

  f32x4 acc[8][4];
#pragma unroll
  for (int i = 0; i < 8; i++)
#pragma unroll
    for (int j = 0; j < 4; j++) acc[i][j] = f32x4{0.f, 0.f, 0.f, 0.f};

  const char* Agb = (const char*)(A  + (size_t)(mt * 256) * 1024);
  const char* Bgb = (const char*)(Bt + (size_t)(nt * 256) * 1024);
  const int srow0 = wid * 32 + (lane >> 2);
  const int srow1 = srow0 + 16;
  const size_t gs0 = (size_t)srow0 * 2048 + (((lane & 3) ^ ((srow0 >> 1) & 3)) << 4);
  const size_t gs1 = (size_t)srow1 * 2048 + (((lane & 3) ^ ((srow1 >> 1) & 3)) << 4);
  const int ld0 = wid * 2048, ld1 = wid * 2048 + 1024;

  int offA[8], offB[4];
#pragma unroll
  for (int i = 0; i < 8; i++) {
    int r = wr * 128 + i * 16 + col;
    offA[i] = r * 64 + ((kg ^ ((r >> 1) & 3)) << 4);
  }
#pragma unroll
  for (int j = 0; j < 4; j++) {
    int r = wc * 64 + j * 16 + col;
    offB[j] = r * 64 + ((kg ^ ((r >> 1) & 3)) << 4);
  }

#define STAGE_OP(gbase, dstbase, kt1, kh)  do {                                  \
    const size_t kb_ = (size_t)(kt1) * 128 + (kh) * 64;                          \
    GLD_LDS(gbase + gs0 + kb_, dstbase + (kh) * 16384 + ld0);                    \
    GLD_LDS(gbase + gs1 + kb_, dstbase + (kh) * 16384 + ld1);                    \
  } while (0)

  half8 bf[4];
#define QPH(IH, KH, PBO, DOW, WN, DOSTG, SGB, SDB, SKT, SKH)  do {               \
    if (DOW) { asm volatile("s_waitcnt vmcnt(" #WN ")" ::: "memory"); }          \
    __builtin_amdgcn_s_barrier();                                                \
    __builtin_amdgcn_sched_barrier(0);                                           \
    const char* Ab_ = smA + (PBO) + (KH) * 16384;                                \
    const char* Bb_ = smB + (PBO) + (KH) * 16384;                                \
    if (IH == 0) {                                                               \
      _Pragma("unroll")                                                          \
      for (int j_ = 0; j_ < 4; j_++) bf[j_] = *(const half8*)(Bb_ + offB[j_]);   \
    }                                                                            \
    half8 af_[4];                                                                \
    _Pragma("unroll")                                                            \
    for (int q_ = 0; q_ < 4; q_++) af_[q_] = *(const half8*)(Ab_ + offA[(IH)*4 + q_]); \
    if (DOSTG) STAGE_OP(SGB, SDB, SKT, SKH);                                     \
    __builtin_amdgcn_s_setprio(1);                                               \
    _Pragma("unroll")                                                            \
    for (int q_ = 0; q_ < 4; q_++)                                               \
      _Pragma("unroll")                                                          \
      for (int j_ = 0; j_ < 4; j_++)                                             \
        acc[(IH)*4 + q_][j_] =                                                   \
          __builtin_amdgcn_mfma_f32_16x16x32_f16(af_[q_], bf[j_], acc[(IH)*4 + q_][j_], 0, 0, 0); \
    __builtin_amdgcn_s_setprio(0);                                               \
  } while (0)

  STAGE_OP(Agb, smA + 0, 0, 0);
  STAGE_OP(Bgb, smB + 0, 0, 0);
  STAGE_OP(Agb, smA + 0, 0, 1);
  STAGE_OP(Bgb, smB + 0, 0, 1);

  for (int kt = 0; kt < 15; ++kt) {
    const int pbo = (kt & 1) * 32768;
    const int qbo = ((kt & 1) ^ 1) * 32768;
    QPH(0, 0, pbo, 1, 4, 1, Agb, smA + qbo, kt + 1, 0);
    QPH(1, 0, pbo, 0, 0, 1, Bgb, smB + qbo, kt + 1, 0);
    QPH(0, 1, pbo, 1, 4, 1, Agb, smA + qbo, kt + 1, 1);
    QPH(1, 1, pbo, 0, 0, 1, Bgb, smB + qbo, kt + 1, 1);
  }
  {
    const int pbo = 32768;
    QPH(0, 0, pbo, 1, 4, 0, Agb, smA, 0, 0);
    QPH(1, 0, pbo, 0, 0, 0, Agb, smA, 0, 0);
    QPH(0, 1, pbo, 1, 0, 0, Agb, smA, 0, 0);
    QPH(1, 1, pbo, 0, 0, 0, Agb, smA, 0, 0);
  }
#undef QPH
#undef STAGE_OP

  // ---- epilogue: 2-pass LDS repack (stride 264 halves), coalesced stores ----
  __syncthreads();
  half_t* Tl = (half_t*)smem;
  const int sec = nt >> 2;
  const int b = mt >> 3;
#pragma unroll 1
  for (int pass = 0; pass < 2; ++pass) {
    if (sec < 2) {
      if (wr == pass) {
#pragma unroll
        for (int fi = 0; fi < 8; fi++)
#pragma unroll
          for (int fj = 0; fj < 4; fj++) {
            int nn = wc * 64 + fj * 16 + col;
            float bv = bias[nt * 256 + nn];
#pragma unroll
            for (int r = 0; r < 4; r++) {
              int rl = fi * 16 + kg * 4 + r;
              float v = acc[fi][fj][r] + bv;
              if (sec == 0) v *= K2LOG;
              Tl[rl * 264 + nn] = (half_t)v;
            }
          }
      }
      __syncthreads();
      const int row = tid >> 2, chunk = tid & 3;
      const half_t* src = Tl + row * 264 + chunk * 64;
      const int m = mt * 256 + pass * 128 + row;
      const int t = m & 2047;
      const int bh2 = b * 16 + (nt & 3) * 4 + chunk;
      half_t* d = (sec == 0 ? qh : kh) + ((size_t)bh2 * TSEQ + t) * 64;
#pragma unroll
      for (int k = 0; k < 8; k++)
        *(half8*)(d + k * 8) = *(const half8*)(src + k * 8);
      __syncthreads();
    } else {
      if ((wc >> 1) == pass) {
#pragma unroll
        for (int fi = 0; fi < 8; fi++)
#pragma unroll
          for (int fj = 0; fj < 4; fj++) {
            int nn = wc * 64 + fj * 16 + col;        // absolute 0..255
            float bv = bias[nt * 256 + nn];
            int nnl = nn - pass * 128;               // 0..127
#pragma unroll
            for (int r = 0; r < 4; r++) {
              int ml = wr * 128 + fi * 16 + kg * 4 + r;   // 0..255
              Tl[nnl * 264 + ml] = (half_t)(acc[fi][fj][r] + bv);
            }
          }
      }
      __syncthreads();
      const int nnl = tid >> 2, mchunk = tid & 3;
      const half_t* src = Tl + nnl * 264 + mchunk * 64;
      const int nn = pass * 128 + nnl;
      const int bh2 = b * 16 + (nt & 3) * 4 + (nn >> 6);
      const int dd = nn & 63;
      const int t0 = (mt & 7) * 256 + mchunk * 64;
      half_t* d = vt + ((size_t)bh2 * 64 + dd) * TSEQ + t0;
#pragma unroll
      for (int k = 0; k < 8; k++)
        *(half8*)(d + k * 8) = *(const half8*)(src + k * 8);
      __syncthreads();
    }
  }
}

// ---------- fused flash attention: no-max softmax, K via LDS, V direct-from-L1/L2 ----------
// V fragment loads issued at tile top into registers (T14): HBM/L2 latency hides
// under QK+softmax; PV is pure-register MFMA. DS traffic halves vs staged V.
__global__ __launch_bounds__(512, 4) void k_attn(
    const half_t* __restrict__ qh, const half_t* __restrict__ kh,
    const half_t* __restrict__ vt, half_t* __restrict__ ctx) {
  extern __shared__ __align__(16) char smem[];   // 64 KB (K staging + merge)
  const int p = blockIdx.x;
  const int l = (p & 7) * 64 + (p >> 3);
  const int qt = l & 15, bh = l >> 4;
  const int tid = threadIdx.x, lane = tid & 63, wid = tid >> 6;
  const int l31 = lane & 31, hi = lane >> 5;
  const int khalf = wid >> 2;
  const int wq = wid & 3;

  const int q = qt * 128 + wq * 32 + l31;
  const half_t* qbase = qh + ((size_t)bh * TSEQ + q) * 64 + hi * 8;
  half8 qf[4];
#pragma unroll
  for (int kc = 0; kc < 4; kc++) qf[kc] = *(const half8*)(qbase + kc * 16);

  f32x16 o0, o1;
#pragma unroll
  for (int r = 0; r < 16; r++) { o0[r] = 0.f; o1[r] = 0.f; }
  float l_run = 0.f;

  const char* kgb = (const char*)kh + (size_t)bh * 262144 + (size_t)khalf * 131072;
  const char* vgb = (const char*)vt + (size_t)bh * 262144 + khalf * 2048;
  char* sbK = smem + khalf * 16384;          // K dbuf 2 x 8KB per khalf
  const int s7 = lane & 7;
  const int rA = wq * 16 + (lane >> 3);
  const int rB = rA + 8;
  const size_t gK0 = (size_t)rA * 128 + ((s7 ^ (rA & 7)) << 4);
  const size_t gK1 = (size_t)rB * 128 + ((s7 ^ (rB & 7)) << 4);
  const int lds0 = wq * 2048, lds1 = wq * 2048 + 1024;

  auto stage = [&](int t) {
    const int buf = (t & 1) * 8192;
    GLD_LDS(kgb + (size_t)t * 8192 + gK0, sbK + buf + lds0);
    GLD_LDS(kgb + (size_t)t * 8192 + gK1, sbK + buf + lds1);
  };

  stage(0);
  __syncthreads();

  const int swr = (l31 & 7) << 4;
  const int rb  = l31 * 128;
  const int hb  = hi * 16;
  const char* vrow0 = vgb + (size_t)l31 * 4096 + hb;   // d = l31 row base

  for (int t = 0; t < 16; ++t) {
    if (t < 15) stage(t + 1);
    // ---- issue V fragment loads early (land under QK+softmax) ----
    half8 vf0[4], vf1[4];
    {
      const char* vr = vrow0 + (size_t)t * 128;
#pragma unroll
      for (int kc2 = 0; kc2 < 4; kc2++) {
        vf0[kc2] = *(const half8*)(vr + kc2 * 32);
        vf1[kc2] = *(const half8*)(vr + (size_t)32 * 4096 + kc2 * 32);
      }
    }
    const char* lk = sbK + (t & 1) * 8192;

    // ---- S^T = K * Q^T ----
    f32x16 s0, s1;
#pragma unroll
    for (int r = 0; r < 16; r++) { s0[r] = 0.f; s1[r] = 0.f; }
    __builtin_amdgcn_s_setprio(1);
#pragma unroll
    for (int kc = 0; kc < 4; kc++) {
      const int off = (kc * 32 + hb) ^ swr;
      half8 kf0 = *(const half8*)(lk + rb + off);
      half8 kf1 = *(const half8*)(lk + rb + 4096 + off);
      s0 = __builtin_amdgcn_mfma_f32_32x32x16_f16(kf0, qf[kc], s0, 0, 0, 0);
      s1 = __builtin_amdgcn_mfma_f32_32x32x16_f16(kf1, qf[kc], s1, 0, 0, 0);
    }
    __builtin_amdgcn_s_setprio(0);

    // ---- softmax numerators (Q pre-scaled -> exp2 direct) ----
#pragma unroll
    for (int r = 0; r < 16; r++) s0[r] = EXP2F(s0[r]);
#pragma unroll
    for (int r = 0; r < 16; r++) s1[r] = EXP2F(s1[r]);
    float a16[16];
#pragma unroll
    for (int r = 0; r < 16; r++) a16[r] = s0[r] + s1[r];
#pragma unroll
    for (int r = 0; r < 8; r++) a16[r] += a16[r + 8];
#pragma unroll
    for (int r = 0; r < 4; r++) a16[r] += a16[r + 4];
    float sum = (a16[0] + a16[1]) + (a16[2] + a16[3]);
    sum += partner32(sum, hi);
    l_run += sum;

    // ---- P -> f16 B-fragments: pack + permlane32_swap ----
    half8 pf[4];
    {
      unsigned x0 = pk2(s0[0],  s0[1]),  x1 = pk2(s0[2],  s0[3]);
      unsigned z0 = pk2(s0[4],  s0[5]),  z1 = pk2(s0[6],  s0[7]);
      pl32(x0, z0); pl32(x1, z1);
      pf[0] = frag_from(x0, x1, z0, z1);
      unsigned x2 = pk2(s0[8],  s0[9]),  x3 = pk2(s0[10], s0[11]);
      unsigned z2 = pk2(s0[12], s0[13]), z3 = pk2(s0[14], s0[15]);
      pl32(x2, z2); pl32(x3, z3);
      pf[1] = frag_from(x2, x3, z2, z3);
    }
    {
      unsigned x0 = pk2(s1[0],  s1[1]),  x1 = pk2(s1[2],  s1[3]);
      unsigned z0 = pk2(s1[4],  s1[5]),  z1 = pk2(s1[6],  s1[7]);
      pl32(x0, z0); pl32(x1, z1);
      pf[2] = frag_from(x0, x1, z0, z1);
      unsigned x2 = pk2(s1[8],  s1[9]),  x3 = pk2(s1[10], s1[11]);
      unsigned z2 = pk2(s1[12], s1[13]), z3 = pk2(s1[14], s1[15]);
      pl32(x2, z2); pl32(x3, z3);
      pf[3] = frag_from(x2, x3, z2, z3);
    }

    // ---- O^T += V^T * P^T (V in registers) ----
    __builtin_amdgcn_s_setprio(1);
#pragma unroll
    for (int kc2 = 0; kc2 < 4; kc2++) {
      o0 = __builtin_amdgcn_mfma_f32_32x32x16_f16(vf0[kc2], pf[kc2], o0, 0, 0, 0);
      o1 = __builtin_amdgcn_mfma_f32_32x32x16_f16(vf1[kc2], pf[kc2], o1, 0, 0, 0);
    }
    __builtin_amdgcn_s_setprio(0);
    __syncthreads();
  }

  // ---- cross-half merge via LDS (simple add: common scale) ----
  float* ob = (float*)smem + wq * 2176;           // [33 rows][64 lanes]
  if (khalf == 1) {
#pragma unroll
    for (int r = 0; r < 16; r++) {
      ob[r * 64 + lane]        = o0[r];
      ob[(r + 16) * 64 + lane] = o1[r];
    }
    ob[32 * 64 + lane] = l_run;
  }
  __syncthreads();
  if (khalf == 0) {
    float lT = l_run + ob[32 * 64 + lane];
    const float inv = 1.f / fmaxf(lT, 1e-12f);
    const int b = bh >> 4, h = bh & 15;
    half_t* cbp = ctx + ((size_t)(b * TSEQ + q)) * DMODEL + h * 64 + hi * 4;
#pragma unroll
    for (int g = 0; g < 4; g++) {
      half4 h0, h1;
#pragma unroll
      for (int j = 0; j < 4; j++) {
        float v0 = o0[4 * g + j] + ob[(4 * g + j) * 64 + lane];
        float v1 = o1[4 * g + j] + ob[(16 + 4 * g + j) * 64 + lane];
        h0[j] = (half_t)(v0 * inv);
        h1[j] = (half_t)(v1 * inv);
      }
      *(half4*)(cbp + 8 * g)      = h0;
      *(half4*)(cbp + 32 + 8 * g) = h1;
    }
  }
}

// ---------- output projection: 128x64 tile, 3-deep pipeline, counted vmcnt ----------
__global__ __launch_bounds__(256, 4) void k_gemm_proj(
    const half_t* __restrict__ A,   // ctx [4096][1024]
    const half_t* __restrict__ Bt,  // Wproj^T [1024][1024]
    const float* __restrict__ bias, float* __restrict__ out) {
  __shared__ __align__(16) char As[24576];  // 3 x 8KB (128 rows x 64B)
  __shared__ __align__(16) char Bs[12288];  // 3 x 4KB (64 rows x 64B)
  int mt = blockIdx.y, nt = blockIdx.x;
  int tid = threadIdx.x, lane = tid & 63, wid = tid >> 6;
  int wm = (wid >> 1) * 64, wn = (wid & 1) * 32;
  int col = lane & 15, kg = lane >> 4;
  f32x4 acc[4][2];
#pragma unroll
  for (int i = 0; i < 4; i++)
#pragma unroll
    for (int j = 0; j < 2; j++) acc[i][j] = f32x4{0.f, 0.f, 0.f, 0.f};

  const char* Ab = (const char*)(A  + (size_t)(mt * 128) * 1024);
  const char* Bb = (const char*)(Bt + (size_t)(nt * 64) * 1024);
  const int srow0 = wid * 32 + (lane >> 2);
  const int srow1 = srow0 + 16;
  const int sc0 = ((lane & 3) ^ ((srow0 >> 1) & 3)) << 4;
  const int sc1 = ((lane & 3) ^ ((srow1 >> 1) & 3)) << 4;
  const size_t goA0 = (size_t)srow0 * 2048 + sc0;
  const size_t goA1 = (size_t)srow1 * 2048 + sc1;
  const int lbA0 = wid * 2048, lbA1 = wid * 2048 + 1024;
  const int brow = tid >> 2;
  const int bcs = ((lane & 3) ^ ((brow >> 1) & 3)) << 4;
  const size_t goB = (size_t)brow * 2048 + bcs;
  const int lbB = wid * 1024;

  auto stage = [&](int kk) {
    const size_t ko = (size_t)kk * 64;
    GLD_LDS(Ab + goA0 + ko, As + (kk % 3) * 8192 + lbA0);
    GLD_LDS(Ab + goA1 + ko, As + (kk % 3) * 8192 + lbA1);
    GLD_LDS(Bb + goB  + ko, Bs + (kk % 3) * 4096 + lbB);
  };

  stage(0);
  stage(1);

#define PROJ_BODY(T)                                                         \
  do {                                                                       \
    if ((T) + 2 < 32) stage((T) + 2);                                        \
    const char* Ac = As + ((T) % 3) * 8192;                                  \
    const char* Bc = Bs + ((T) % 3) * 4096;                                  \
    half8 af[4], bf[2];                                                      \
    _Pragma("unroll")                                                        \
    for (int i = 0; i < 4; i++) {                                            \
      int r = wm + i * 16 + col;                                             \
      af[i] = *(const half8*)(Ac + r * 64 + ((kg ^ ((r >> 1) & 3)) << 4));   \
    }                                                                        \
    _Pragma("unroll")                                                        \
    for (int j = 0; j < 2; j++) {                                            \
      int r = wn + j * 16 + col;                                             \
      bf[j] = *(const half8*)(Bc + r * 64 + ((kg ^ ((r >> 1) & 3)) << 4));   \
    }                                                                        \
    __builtin_amdgcn_s_setprio(1);                                           \
    _Pragma("unroll")                                                        \
    for (int i = 0; i < 4; i++)                                              \
      _Pragma("unroll")                                                      \
      for (int j = 0; j < 2; j++)                                            \
        acc[i][j] = __builtin_amdgcn_mfma_f32_16x16x32_f16(af[i], bf[j], acc[i][j], 0, 0, 0); \
    __builtin_amdgcn_s_setprio(0);                                           \
  } while (0)

  for (int t = 0; t < 31; t++) {
    asm volatile("s_waitcnt vmcnt(3)" ::: "memory");
    __builtin_amdgcn_s_barrier();
    __builtin_amdgcn_sched_barrier(0);
    PROJ_BODY(t);
  }
  asm volatile("s_waitcnt vmcnt(0)" ::: "memory");
  __builtin_amdgcn_s_barrier();
  __builtin_amdgcn_sched_barrier(0);
  PROJ_BODY(31);
#undef PROJ_BODY

#pragma unroll
  for (int i = 0; i < 4; i++)
#pragma unroll
    for (int j = 0; j < 2; j++) {
      int n = nt * 64 + wn + j * 16 + col;
      float bv = bias[n];
#pragma unroll
      for (int r = 0; r < 4; r++) {
        int m = mt * 128 + wm + i * 16 + kg * 4 + r;
        out[(size_t)m * DMODEL + n] = acc[i][j][r] + bv;
      }
    }
}

extern "C" void kernel_launch(void* const* d_in, const int* in_sizes, int n_in,
                              void* d_out, int out_size, void* d_ws, size_t ws_size,
                              hipStream_t stream) {
  const float* x     = (const float*)d_in[0];
  const float* gamma = (const float*)d_in[1];
  const float* beta  = (const float*)d_in[2];
  const float* Wqkv  = (const float*)d_in[3];
  const float* bqkv  = (const float*)d_in[4];
  const float* Wproj = (const float*)d_in[5];
  const float* bproj = (const float*)d_in[6];
  float* out = (float*)d_out;

  char* ws = (char*)d_ws;              // 48 MB used
  half_t* xn  = (half_t*)(ws);                       // 8 MB
  half_t* wqt = (half_t*)(ws + ((size_t)8  << 20));  // 6 MB
  half_t* wpt = (half_t*)(ws + ((size_t)14 << 20));  // 2 MB
  half_t* qh  = (half_t*)(ws + ((size_t)16 << 20));  // 8 MB
  half_t* kh  = (half_t*)(ws + ((size_t)24 << 20));  // 8 MB
  half_t* vt  = (half_t*)(ws + ((size_t)32 << 20));  // 8 MB
  half_t* ctx = (half_t*)(ws + ((size_t)40 << 20));  // 8 MB

  k_prep<<<8192, 256, 0, stream>>>(x, gamma, beta, xn, Wqkv, wqt, Wproj, wpt);
  k_gemm_qkv<<<192, 512, 131072, stream>>>(xn, wqt, bqkv, qh, kh, vt);
  k_attn<<<512, 512, 65536, stream>>>(qh, kh, vt, ctx);
  k_gemm_proj<<<dim3(16, 32), 256, 0, stream>>>(ctx, wpt, bproj, out);
}

// Round 16
// 111.564 us; speedup vs baseline: 1.6029x; 1.6029x over previous
//
#include <hip/hip_runtime.h>

typedef _Float16 half_t;
typedef __attribute__((ext_vector_type(8))) _Float16 half8;
typedef __attribute__((ext_vector_type(4))) _Float16 half4;
typedef __attribute__((ext_vector_type(4))) float f32x4;
typedef __attribute__((ext_vector_type(16))) float f32x16;

#define TSEQ   2048
#define DMODEL 1024
#define K2LOG  0.18033688011116016f   /* 0.125 * log2(e) */

#if __has_builtin(__builtin_amdgcn_exp2f)
#define EXP2F(x) __builtin_amdgcn_exp2f(x)
#else
#define EXP2F(x) __expf(0.6931471805599453f * (x))
#endif

__device__ inline unsigned pk2(float a, float b) {
  auto h = __builtin_amdgcn_cvt_pkrtz(a, b);   // __fp16 ext_vector(2)
  return __builtin_bit_cast(unsigned, h);
}
__device__ inline half8 frag_from(unsigned a, unsigned b, unsigned c, unsigned d) {
  int4 t; t.x = (int)a; t.y = (int)b; t.z = (int)c; t.w = (int)d;
  return __builtin_bit_cast(half8, t);
}

#if __has_builtin(__builtin_amdgcn_permlane32_swap)
__device__ inline void pl32(unsigned &a, unsigned &b) {
  auto r = __builtin_amdgcn_permlane32_swap(a, b, false, false);
  a = (unsigned)r[0]; b = (unsigned)r[1];
}
#else
__device__ inline void pl32(unsigned &a, unsigned &b) {
  const int hi = (threadIdx.x & 63) >> 5;
  unsigned sa = __shfl_xor(a, 32), sb = __shfl_xor(b, 32);
  unsigned na = hi ? sb : a;
  unsigned nb = hi ? b : sa;
  a = na; b = nb;
}
#endif
__device__ inline float partner32(float v, int hi) {
  unsigned a = __builtin_bit_cast(unsigned, v), b = a;
  pl32(a, b);
  return __builtin_bit_cast(float, hi ? a : b);
}

// ================== async global->LDS staging ==================
#define GLD_LDS(g, l) \
  __builtin_amdgcn_global_load_lds((const __attribute__((address_space(1))) void*)(g), \
                                   (__attribute__((address_space(3))) void*)(l), 16, 0, 0)

// ---------- fused prep: LN (blocks 0..4095) + W transposes (blocks 4096..8191) ----------
__global__ void k_prep(const float* __restrict__ x, const float* __restrict__ gamma,
                       const float* __restrict__ beta, half_t* __restrict__ xn,
                       const float* __restrict__ wqkv, half_t* __restrict__ wqt,
                       const float* __restrict__ wproj, half_t* __restrict__ wpt) {
  __shared__ float sm[32 * 33];
  const int blk = blockIdx.x;
  if (blk < 4096) {
    int row = blk, t = threadIdx.x;
    const float4 v = *(const float4*)(x + (size_t)row * DMODEL + t * 4);
    float s  = v.x + v.y + v.z + v.w;
    float ss = v.x * v.x + v.y * v.y + v.z * v.z + v.w * v.w;
#pragma unroll
    for (int off = 32; off >= 1; off >>= 1) {
      s  += __shfl_down(s, off);
      ss += __shfl_down(ss, off);
    }
    int wid = t >> 6;
    if ((t & 63) == 0) { sm[wid] = s; sm[4 + wid] = ss; }
    __syncthreads();
    s  = sm[0] + sm[1] + sm[2] + sm[3];
    ss = sm[4] + sm[5] + sm[6] + sm[7];
    float mu   = s * (1.f / DMODEL);
    float var  = ss * (1.f / DMODEL) - mu * mu;
    float rstd = rsqrtf(var + 1e-5f);
    float4 g = *(const float4*)(gamma + t * 4);
    float4 b = *(const float4*)(beta  + t * 4);
    half4 o;
    o.x = (half_t)((v.x - mu) * rstd * g.x + b.x);
    o.y = (half_t)((v.y - mu) * rstd * g.y + b.y);
    o.z = (half_t)((v.z - mu) * rstd * g.z + b.z);
    o.w = (half_t)((v.w - mu) * rstd * g.w + b.w);
    *(half4*)(xn + (size_t)row * DMODEL + t * 4) = o;
  } else {
    const int bx2 = blk - 4096;
    const int bx = bx2 & 127, by = bx2 >> 7;
    const float* in;
    half_t* out;
    int n0, N;
    if (bx < 96) { in = wqkv; out = wqt; n0 = bx * 32; N = 3072; }
    else         { in = wproj; out = wpt; n0 = (bx - 96) * 32; N = 1024; }
    int k0 = by * 32;
    int tx = threadIdx.x & 31, ty = threadIdx.x >> 5;
#pragma unroll
    for (int i = 0; i < 32; i += 8)
      sm[(ty + i) * 33 + tx] = in[(size_t)(k0 + ty + i) * N + n0 + tx];
    __syncthreads();
#pragma unroll
    for (int i = 0; i < 32; i += 8)
      out[(size_t)(n0 + ty + i) * 1024 + k0 + tx] = (half_t)sm[tx * 33 + ty + i];
  }
}

// ---------- QKV GEMM: 256x256 tile, 8-phase interleave, counted vmcnt (T3+T4) ----------
__global__ __launch_bounds__(512, 2) void k_gemm_qkv(
    const half_t* __restrict__ A,   // xn [4096][1024]
    const half_t* __restrict__ Bt,  // Wqkv^T [3072][1024]
    const float* __restrict__ bias, // [3072]
    half_t* __restrict__ qh, half_t* __restrict__ kh, half_t* __restrict__ vt) {
  extern __shared__ __align__(16) char smem[];   // 128 KB
  char* smA = smem;
  char* smB = smem + 65536;

  const int p = blockIdx.x;
  const int lb = (p & 7) * 24 + (p >> 3);
  const int mt = lb & 15, nt = lb >> 4;      // mt 0..15, nt 0..11

  const int tid = threadIdx.x, lane = tid & 63, wid = tid >> 6;
  const int wr = wid >> 2, wc = wid & 3;
  const int col = lane & 15, kg = lane >> 4;

  f32x4 acc[8][4];
#pragma unroll
  for (int i = 0; i < 8; i++)
#pragma unroll
    for (int j = 0; j < 4; j++) acc[i][j] = f32x4{0.f, 0.f, 0.f, 0.f};

  const char* Agb = (const char*)(A  + (size_t)(mt * 256) * 1024);
  const char* Bgb = (const char*)(Bt + (size_t)(nt * 256) * 1024);
  const int srow0 = wid * 32 + (lane >> 2);
  const int srow1 = srow0 + 16;
  const size_t gs0 = (size_t)srow0 * 2048 + (((lane & 3) ^ ((srow0 >> 1) & 3)) << 4);
  const size_t gs1 = (size_t)srow1 * 2048 + (((lane & 3) ^ ((srow1 >> 1) & 3)) << 4);
  const int ld0 = wid * 2048, ld1 = wid * 2048 + 1024;

  int offA[8], offB[4];
#pragma unroll
  for (int i = 0; i < 8; i++) {
    int r = wr * 128 + i * 16 + col;
    offA[i] = r * 64 + ((kg ^ ((r >> 1) & 3)) << 4);
  }
#pragma unroll
  for (int j = 0; j < 4; j++) {
    int r = wc * 64 + j * 16 + col;
    offB[j] = r * 64 + ((kg ^ ((r >> 1) & 3)) << 4);
  }

#define STAGE_OP(gbase, dstbase, kt1, kh)  do {                                  \
    const size_t kb_ = (size_t)(kt1) * 128 + (kh) * 64;                          \
    GLD_LDS(gbase + gs0 + kb_, dstbase + (kh) * 16384 + ld0);                    \
    GLD_LDS(gbase + gs1 + kb_, dstbase + (kh) * 16384 + ld1);                    \
  } while (0)

  half8 bf[4];
#define QPH(IH, KH, PBO, DOW, WN, DOSTG, SGB, SDB, SKT, SKH)  do {               \
    if (DOW) { asm volatile("s_waitcnt vmcnt(" #WN ")" ::: "memory"); }          \
    __builtin_amdgcn_s_barrier();                                                \
    __builtin_amdgcn_sched_barrier(0);                                           \
    const char* Ab_ = smA + (PBO) + (KH) * 16384;                                \
    const char* Bb_ = smB + (PBO) + (KH) * 16384;                                \
    if (IH == 0) {                                                               \
      _Pragma("unroll")                                                          \
      for (int j_ = 0; j_ < 4; j_++) bf[j_] = *(const half8*)(Bb_ + offB[j_]);   \
    }                                                                            \
    half8 af_[4];                                                                \
    _Pragma("unroll")                                                            \
    for (int q_ = 0; q_ < 4; q_++) af_[q_] = *(const half8*)(Ab_ + offA[(IH)*4 + q_]); \
    if (DOSTG) STAGE_OP(SGB, SDB, SKT, SKH);                                     \
    __builtin_amdgcn_s_setprio(1);                                               \
    _Pragma("unroll")                                                            \
    for (int q_ = 0; q_ < 4; q_++)                                               \
      _Pragma("unroll")                                                          \
      for (int j_ = 0; j_ < 4; j_++)                                             \
        acc[(IH)*4 + q_][j_] =                                                   \
          __builtin_amdgcn_mfma_f32_16x16x32_f16(af_[q_], bf[j_], acc[(IH)*4 + q_][j_], 0, 0, 0); \
    __builtin_amdgcn_s_setprio(0);                                               \
  } while (0)

  STAGE_OP(Agb, smA + 0, 0, 0);
  STAGE_OP(Bgb, smB + 0, 0, 0);
  STAGE_OP(Agb, smA + 0, 0, 1);
  STAGE_OP(Bgb, smB + 0, 0, 1);

  for (int kt = 0; kt < 15; ++kt) {
    const int pbo = (kt & 1) * 32768;
    const int qbo = ((kt & 1) ^ 1) * 32768;
    QPH(0, 0, pbo, 1, 4, 1, Agb, smA + qbo, kt + 1, 0);
    QPH(1, 0, pbo, 0, 0, 1, Bgb, smB + qbo, kt + 1, 0);
    QPH(0, 1, pbo, 1, 4, 1, Agb, smA + qbo, kt + 1, 1);
    QPH(1, 1, pbo, 0, 0, 1, Bgb, smB + qbo, kt + 1, 1);
  }
  {
    const int pbo = 32768;
    QPH(0, 0, pbo, 1, 4, 0, Agb, smA, 0, 0);
    QPH(1, 0, pbo, 0, 0, 0, Agb, smA, 0, 0);
    QPH(0, 1, pbo, 1, 0, 0, Agb, smA, 0, 0);
    QPH(1, 1, pbo, 0, 0, 0, Agb, smA, 0, 0);
  }
#undef QPH
#undef STAGE_OP

  // ---- epilogue: 2-pass LDS repack (stride 264 halves), coalesced stores ----
  __syncthreads();
  half_t* Tl = (half_t*)smem;
  const int sec = nt >> 2;
  const int b = mt >> 3;
#pragma unroll 1
  for (int pass = 0; pass < 2; ++pass) {
    if (sec < 2) {
      if (wr == pass) {
#pragma unroll
        for (int fi = 0; fi < 8; fi++)
#pragma unroll
          for (int fj = 0; fj < 4; fj++) {
            int nn = wc * 64 + fj * 16 + col;
            float bv = bias[nt * 256 + nn];
#pragma unroll
            for (int r = 0; r < 4; r++) {
              int rl = fi * 16 + kg * 4 + r;
              float v = acc[fi][fj][r] + bv;
              if (sec == 0) v *= K2LOG;
              Tl[rl * 264 + nn] = (half_t)v;
            }
          }
      }
      __syncthreads();
      const int row = tid >> 2, chunk = tid & 3;
      const half_t* src = Tl + row * 264 + chunk * 64;
      const int m = mt * 256 + pass * 128 + row;
      const int t = m & 2047;
      const int bh2 = b * 16 + (nt & 3) * 4 + chunk;
      half_t* d = (sec == 0 ? qh : kh) + ((size_t)bh2 * TSEQ + t) * 64;
#pragma unroll
      for (int k = 0; k < 8; k++)
        *(half8*)(d + k * 8) = *(const half8*)(src + k * 8);
      __syncthreads();
    } else {
      if ((wc >> 1) == pass) {
#pragma unroll
        for (int fi = 0; fi < 8; fi++)
#pragma unroll
          for (int fj = 0; fj < 4; fj++) {
            int nn = wc * 64 + fj * 16 + col;        // absolute 0..255
            float bv = bias[nt * 256 + nn];
            int nnl = nn - pass * 128;               // 0..127
#pragma unroll
            for (int r = 0; r < 4; r++) {
              int ml = wr * 128 + fi * 16 + kg * 4 + r;   // 0..255
              Tl[nnl * 264 + ml] = (half_t)(acc[fi][fj][r] + bv);
            }
          }
      }
      __syncthreads();
      const int nnl = tid >> 2, mchunk = tid & 3;
      const half_t* src = Tl + nnl * 264 + mchunk * 64;
      const int nn = pass * 128 + nnl;
      const int bh2 = b * 16 + (nt & 3) * 4 + (nn >> 6);
      const int dd = nn & 63;
      const int t0 = (mt & 7) * 256 + mchunk * 64;
      half_t* d = vt + ((size_t)bh2 * 64 + dd) * TSEQ + t0;
#pragma unroll
      for (int k = 0; k < 8; k++)
        *(half8*)(d + k * 8) = *(const half8*)(src + k * 8);
      __syncthreads();
    }
  }
}

// ---------- fused flash attention (round-14 verified: K+V LDS-staged, no-max,
// pre-scaled Q, XCD swizzle; 45.3 us) ----------
__global__ __launch_bounds__(512, 4) void k_attn(
    const half_t* __restrict__ qh, const half_t* __restrict__ kh,
    const half_t* __restrict__ vt, half_t* __restrict__ ctx) {
  extern __shared__ __align__(16) char smem[];   // 64 KB
  const int p = blockIdx.x;
  const int l = (p & 7) * 64 + (p >> 3);
  const int qt = l & 15, bh = l >> 4;
  const int tid = threadIdx.x, lane = tid & 63, wid = tid >> 6;
  const int l31 = lane & 31, hi = lane >> 5;
  const int khalf = wid >> 2;
  const int wq = wid & 3;

  const int q = qt * 128 + wq * 32 + l31;
  const half_t* qbase = qh + ((size_t)bh * TSEQ + q) * 64 + hi * 8;
  half8 qf[4];
#pragma unroll
  for (int kc = 0; kc < 4; kc++) qf[kc] = *(const half8*)(qbase + kc * 16);

  f32x16 o0, o1;
#pragma unroll
  for (int r = 0; r < 16; r++) { o0[r] = 0.f; o1[r] = 0.f; }
  float l_run = 0.f;

  const char* kgb = (const char*)kh + (size_t)bh * 262144 + (size_t)khalf * 131072;
  const char* vgb = (const char*)vt + (size_t)bh * 262144 + khalf * 2048;
  char* sbK = smem + khalf * 32768;
  char* sbV = sbK + 16384;
  const int s7 = lane & 7;
  const int rA = wq * 16 + (lane >> 3);
  const int rB = rA + 8;
  const size_t gK0 = (size_t)rA * 128  + ((s7 ^ (rA & 7)) << 4);
  const size_t gK1 = (size_t)rB * 128  + ((s7 ^ (rB & 7)) << 4);
  const size_t gV0 = (size_t)rA * 4096 + ((s7 ^ (rA & 7)) << 4);
  const size_t gV1 = (size_t)rB * 4096 + ((s7 ^ (rB & 7)) << 4);
  const int lds0 = wq * 2048, lds1 = wq * 2048 + 1024;

  auto stage = [&](int t) {
    const int buf = (t & 1) * 8192;
    GLD_LDS(kgb + (size_t)t * 8192 + gK0, sbK + buf + lds0);
    GLD_LDS(kgb + (size_t)t * 8192 + gK1, sbK + buf + lds1);
    GLD_LDS(vgb + (size_t)t * 128  + gV0, sbV + buf + lds0);
    GLD_LDS(vgb + (size_t)t * 128  + gV1, sbV + buf + lds1);
  };

  stage(0);
  __syncthreads();

  const int swr = (l31 & 7) << 4;
  const int rb  = l31 * 128;
  const int hb  = hi * 16;

  for (int t = 0; t < 16; ++t) {
    if (t < 15) stage(t + 1);
    const char* lk = sbK + (t & 1) * 8192;
    const char* lv = sbV + (t & 1) * 8192;

    f32x16 s0, s1;
#pragma unroll
    for (int r = 0; r < 16; r++) { s0[r] = 0.f; s1[r] = 0.f; }
    __builtin_amdgcn_s_setprio(1);
#pragma unroll
    for (int kc = 0; kc < 4; kc++) {
      const int off = (kc * 32 + hb) ^ swr;
      half8 kf0 = *(const half8*)(lk + rb + off);
      half8 kf1 = *(const half8*)(lk + rb + 4096 + off);
      s0 = __builtin_amdgcn_mfma_f32_32x32x16_f16(kf0, qf[kc], s0, 0, 0, 0);
      s1 = __builtin_amdgcn_mfma_f32_32x32x16_f16(kf1, qf[kc], s1, 0, 0, 0);
    }
    __builtin_amdgcn_s_setprio(0);

    // Q pre-scaled by 0.125*log2(e) in qkv epilogue -> exp2 directly.
#pragma unroll
    for (int r = 0; r < 16; r++) s0[r] = EXP2F(s0[r]);
#pragma unroll
    for (int r = 0; r < 16; r++) s1[r] = EXP2F(s1[r]);
    float a16[16];
#pragma unroll
    for (int r = 0; r < 16; r++) a16[r] = s0[r] + s1[r];
#pragma unroll
    for (int r = 0; r < 8; r++) a16[r] += a16[r + 8];
#pragma unroll
    for (int r = 0; r < 4; r++) a16[r] += a16[r + 4];
    float sum = (a16[0] + a16[1]) + (a16[2] + a16[3]);
    sum += partner32(sum, hi);
    l_run += sum;

    half8 pf[4];
    {
      unsigned x0 = pk2(s0[0],  s0[1]),  x1 = pk2(s0[2],  s0[3]);
      unsigned z0 = pk2(s0[4],  s0[5]),  z1 = pk2(s0[6],  s0[7]);
      pl32(x0, z0); pl32(x1, z1);
      pf[0] = frag_from(x0, x1, z0, z1);
      unsigned x2 = pk2(s0[8],  s0[9]),  x3 = pk2(s0[10], s0[11]);
      unsigned z2 = pk2(s0[12], s0[13]), z3 = pk2(s0[14], s0[15]);
      pl32(x2, z2); pl32(x3, z3);
      pf[1] = frag_from(x2, x3, z2, z3);
    }
    {
      unsigned x0 = pk2(s1[0],  s1[1]),  x1 = pk2(s1[2],  s1[3]);
      unsigned z0 = pk2(s1[4],  s1[5]),  z1 = pk2(s1[6],  s1[7]);
      pl32(x0, z0); pl32(x1, z1);
      pf[2] = frag_from(x0, x1, z0, z1);
      unsigned x2 = pk2(s1[8],  s1[9]),  x3 = pk2(s1[10], s1[11]);
      unsigned z2 = pk2(s1[12], s1[13]), z3 = pk2(s1[14], s1[15]);
      pl32(x2, z2); pl32(x3, z3);
      pf[3] = frag_from(x2, x3, z2, z3);
    }

    __builtin_amdgcn_s_setprio(1);
#pragma unroll
    for (int kc2 = 0; kc2 < 4; kc2++) {
      const int off = (kc2 * 32 + hb) ^ swr;
      half8 vf0 = *(const half8*)(lv + rb + off);
      half8 vf1 = *(const half8*)(lv + rb + 4096 + off);
      o0 = __builtin_amdgcn_mfma_f32_32x32x16_f16(vf0, pf[kc2], o0, 0, 0, 0);
      o1 = __builtin_amdgcn_mfma_f32_32x32x16_f16(vf1, pf[kc2], o1, 0, 0, 0);
    }
    __builtin_amdgcn_s_setprio(0);
    __syncthreads();
  }

  // ---- cross-half merge via LDS (simple add: common scale) ----
  float* ob = (float*)smem + wq * 2176;           // [33 rows][64 lanes]
  if (khalf == 1) {
#pragma unroll
    for (int r = 0; r < 16; r++) {
      ob[r * 64 + lane]        = o0[r];
      ob[(r + 16) * 64 + lane] = o1[r];
    }
    ob[32 * 64 + lane] = l_run;
  }
  __syncthreads();
  if (khalf == 0) {
    float lT = l_run + ob[32 * 64 + lane];
    const float inv = 1.f / fmaxf(lT, 1e-12f);
    const int b = bh >> 4, h = bh & 15;
    half_t* cbp = ctx + ((size_t)(b * TSEQ + q)) * DMODEL + h * 64 + hi * 4;
#pragma unroll
    for (int g = 0; g < 4; g++) {
      half4 h0, h1;
#pragma unroll
      for (int j = 0; j < 4; j++) {
        float v0 = o0[4 * g + j] + ob[(4 * g + j) * 64 + lane];
        float v1 = o1[4 * g + j] + ob[(16 + 4 * g + j) * 64 + lane];
        h0[j] = (half_t)(v0 * inv);
        h1[j] = (half_t)(v1 * inv);
      }
      *(half4*)(cbp + 8 * g)      = h0;
      *(half4*)(cbp + 32 + 8 * g) = h1;
    }
  }
}

// ---------- output projection: 128x64 tile, 3-deep pipeline, XCD swizzle ----------
__global__ __launch_bounds__(256, 4) void k_gemm_proj(
    const half_t* __restrict__ A,   // ctx [4096][1024]
    const half_t* __restrict__ Bt,  // Wproj^T [1024][1024]
    const float* __restrict__ bias, float* __restrict__ out) {
  __shared__ __align__(16) char As[24576];  // 3 x 8KB (128 rows x 64B)
  __shared__ __align__(16) char Bs[12288];  // 3 x 4KB (64 rows x 64B)
  // T1 XCD swizzle: 512 blocks, 512%8==0 -> bijective; each XCD owns 4 mt
  // stripes x all nt (ctx A-panel becomes XCD-local in L2).
  const int p = blockIdx.x;
  const int lb = (p & 7) * 64 + (p >> 3);
  const int nt = lb & 15, mt = lb >> 4;
  int tid = threadIdx.x, lane = tid & 63, wid = tid >> 6;
  int wm = (wid >> 1) * 64, wn = (wid & 1) * 32;
  int col = lane & 15, kg = lane >> 4;
  f32x4 acc[4][2];
#pragma unroll
  for (int i = 0; i < 4; i++)
#pragma unroll
    for (int j = 0; j < 2; j++) acc[i][j] = f32x4{0.f, 0.f, 0.f, 0.f};

  const char* Ab = (const char*)(A  + (size_t)(mt * 128) * 1024);
  const char* Bb = (const char*)(Bt + (size_t)(nt * 64) * 1024);
  const int srow0 = wid * 32 + (lane >> 2);
  const int srow1 = srow0 + 16;
  const int sc0 = ((lane & 3) ^ ((srow0 >> 1) & 3)) << 4;
  const int sc1 = ((lane & 3) ^ ((srow1 >> 1) & 3)) << 4;
  const size_t goA0 = (size_t)srow0 * 2048 + sc0;
  const size_t goA1 = (size_t)srow1 * 2048 + sc1;
  const int lbA0 = wid * 2048, lbA1 = wid * 2048 + 1024;
  const int brow = tid >> 2;
  const int bcs = ((lane & 3) ^ ((brow >> 1) & 3)) << 4;
  const size_t goB = (size_t)brow * 2048 + bcs;
  const int lbB = wid * 1024;

  auto stage = [&](int kk) {
    const size_t ko = (size_t)kk * 64;
    GLD_LDS(Ab + goA0 + ko, As + (kk % 3) * 8192 + lbA0);
    GLD_LDS(Ab + goA1 + ko, As + (kk % 3) * 8192 + lbA1);
    GLD_LDS(Bb + goB  + ko, Bs + (kk % 3) * 4096 + lbB);
  };

  stage(0);
  stage(1);

#define PROJ_BODY(T)                                                         \
  do {                                                                       \
    if ((T) + 2 < 32) stage((T) + 2);                                        \
    const char* Ac = As + ((T) % 3) * 8192;                                  \
    const char* Bc = Bs + ((T) % 3) * 4096;                                  \
    half8 af[4], bf[2];                                                      \
    _Pragma("unroll")                                                        \
    for (int i = 0; i < 4; i++) {                                            \
      int r = wm + i * 16 + col;                                             \
      af[i] = *(const half8*)(Ac + r * 64 + ((kg ^ ((r >> 1) & 3)) << 4));   \
    }                                                                        \
    _Pragma("unroll")                                                        \
    for (int j = 0; j < 2; j++) {                                            \
      int r = wn + j * 16 + col;                                             \
      bf[j] = *(const half8*)(Bc + r * 64 + ((kg ^ ((r >> 1) & 3)) << 4));   \
    }                                                                        \
    __builtin_amdgcn_s_setprio(1);                                           \
    _Pragma("unroll")                                                        \
    for (int i = 0; i < 4; i++)                                              \
      _Pragma("unroll")                                                      \
      for (int j = 0; j < 2; j++)                                            \
        acc[i][j] = __builtin_amdgcn_mfma_f32_16x16x32_f16(af[i], bf[j], acc[i][j], 0, 0, 0); \
    __builtin_amdgcn_s_setprio(0);                                           \
  } while (0)

  for (int t = 0; t < 31; t++) {
    asm volatile("s_waitcnt vmcnt(3)" ::: "memory");
    __builtin_amdgcn_s_barrier();
    __builtin_amdgcn_sched_barrier(0);
    PROJ_BODY(t);
  }
  asm volatile("s_waitcnt vmcnt(0)" ::: "memory");
  __builtin_amdgcn_s_barrier();
  __builtin_amdgcn_sched_barrier(0);
  PROJ_BODY(31);
#undef PROJ_BODY

#pragma unroll
  for (int i = 0; i < 4; i++)
#pragma unroll
    for (int j = 0; j < 2; j++) {
      int n = nt * 64 + wn + j * 16 + col;
      float bv = bias[n];
#pragma unroll
      for (int r = 0; r < 4; r++) {
        int m = mt * 128 + wm + i * 16 + kg * 4 + r;
        out[(size_t)m * DMODEL + n] = acc[i][j][r] + bv;
      }
    }
}

extern "C" void kernel_launch(void* const* d_in, const int* in_sizes, int n_in,
                              void* d_out, int out_size, void* d_ws, size_t ws_size,
                              hipStream_t stream) {
  const float* x     = (const float*)d_in[0];
  const float* gamma = (const float*)d_in[1];
  const float* beta  = (const float*)d_in[2];
  const float* Wqkv  = (const float*)d_in[3];
  const float* bqkv  = (const float*)d_in[4];
  const float* Wproj = (const float*)d_in[5];
  const float* bproj = (const float*)d_in[6];
  float* out = (float*)d_out;

  char* ws = (char*)d_ws;              // 48 MB used
  half_t* xn  = (half_t*)(ws);                       // 8 MB
  half_t* wqt = (half_t*)(ws + ((size_t)8  << 20));  // 6 MB
  half_t* wpt = (half_t*)(ws + ((size_t)14 << 20));  // 2 MB
  half_t* qh  = (half_t*)(ws + ((size_t)16 << 20));  // 8 MB
  half_t* kh  = (half_t*)(ws + ((size_t)24 << 20));  // 8 MB
  half_t* vt  = (half_t*)(ws + ((size_t)32 << 20));  // 8 MB
  half_t* ctx = (half_t*)(ws + ((size_t)40 << 20));  // 8 MB

  k_prep<<<8192, 256, 0, stream>>>(x, gamma, beta, xn, Wqkv, wqt, Wproj, wpt);
  k_gemm_qkv<<<192, 512, 131072, stream>>>(xn, wqt, bqkv, qh, kh, vt);
  k_attn<<<512, 512, 65536, stream>>>(qh, kh, vt, ctx);
  k_gemm_proj<<<512, 256, 0, stream>>>(ctx, wpt, bproj, out);
}